// Round 1
// baseline (1144.568 us; speedup 1.0000x reference)
//
#include <hip/hip_runtime.h>

// LSTMNet: 2-layer LSTM (in=1, hid=32) + linear(32->1), B=2048, T=1024, fp32.
// One wave per batch element: 64 lanes = 32 hidden units x 2 halves.
//   half 0, lane j: gate rows j (i) and 32+j (f)
//   half 1, lane j: gate rows 64+j (g) and 96+j (o)
// All weights in VGPRs (192/lane). h broadcast via v_readlane. 2 waves/SIMD.

constexpr int BATCH = 2048;
constexpr int TLEN  = 1024;
constexpr int HID   = 32;

__device__ __forceinline__ float bcast(float v, int k) {
    return __int_as_float(__builtin_amdgcn_readlane(__float_as_int(v), k));
}
__device__ __forceinline__ float fast_rcp(float v) {
    return __builtin_amdgcn_rcpf(v);
}
__device__ __forceinline__ float sigm(float xv) {
    return fast_rcp(1.0f + __expf(-xv));
}
__device__ __forceinline__ float tanh_fast(float xv) {
    // tanh(x) = 2*sigmoid(2x) - 1
    return __builtin_fmaf(2.0f, fast_rcp(1.0f + __expf(-2.0f * xv)), -1.0f);
}

__global__ __launch_bounds__(256, 2)
void lstm2_kernel(const float* __restrict__ x,
                  const float* __restrict__ Wih0, const float* __restrict__ Whh0,
                  const float* __restrict__ bih0, const float* __restrict__ bhh0,
                  const float* __restrict__ Wih1, const float* __restrict__ Whh1,
                  const float* __restrict__ bih1, const float* __restrict__ bhh1,
                  const float* __restrict__ Wlin, const float* __restrict__ blin,
                  float* __restrict__ out)
{
    const int lane = threadIdx.x & 63;
    const int b    = blockIdx.x * (blockDim.x >> 6) + (threadIdx.x >> 6);
    const int j    = lane & 31;
    const int hi   = lane >> 5;          // 0: i,f rows   1: g,o rows

    const int rowA = hi * 64 + j;        // i (hi=0) / g (hi=1)
    const int rowB = rowA + 32;          // f (hi=0) / o (hi=1)

    // ---- per-lane weights into registers ----
    const float wih0_a = Wih0[rowA];
    const float wih0_b = Wih0[rowB];
    const float ba0 = bih0[rowA] + bhh0[rowA];
    const float bb0 = bih0[rowB] + bhh0[rowB];
    const float ba1 = bih1[rowA] + bhh1[rowA];
    const float bb1 = bih1[rowB] + bhh1[rowB];

    float whh0_a[HID], whh0_b[HID], wih1_a[HID], wih1_b[HID], whh1_a[HID], whh1_b[HID];
    #pragma unroll
    for (int k = 0; k < HID; ++k) {
        whh0_a[k] = Whh0[rowA * HID + k];
        whh0_b[k] = Whh0[rowB * HID + k];
        wih1_a[k] = Wih1[rowA * HID + k];
        wih1_b[k] = Wih1[rowB * HID + k];
        whh1_a[k] = Whh1[rowA * HID + k];
        whh1_b[k] = Whh1[rowB * HID + k];
    }
    const float wl = (hi == 0) ? Wlin[j] : 0.0f;  // only half0 contributes to y-sum
    const float bl = blin[0];

    // activation-"a" selector: half0 -> sigmoid, half1 -> tanh (=2*sigm(2x)-1)
    const float sclA = hi ? -2.0f : -1.0f;
    const float mA   = hi ?  2.0f :  1.0f;
    const float cAdd = hi ? -1.0f :  0.0f;

    float h0 = 0.0f, c0 = 0.0f, h1 = 0.0f, c1 = 0.0f;

    const float* xrow = x   + (size_t)b * TLEN;
    float*       orow = out + (size_t)b * TLEN;

    for (int tc = 0; tc < TLEN / 64; ++tc) {
        const float xchunk = xrow[tc * 64 + lane];   // coalesced, 64 steps' worth
        float ychunk = 0.0f;

        for (int tt = 0; tt < 64; ++tt) {
            const float xt = bcast(xchunk, tt);

            // ================= layer 0 =================
            float ga  = __builtin_fmaf(wih0_a, xt, ba0);
            float gb  = __builtin_fmaf(wih0_b, xt, bb0);
            float ga2 = 0.0f, gb2 = 0.0f;
            #pragma unroll
            for (int k = 0; k < HID; k += 2) {
                const float hk0 = bcast(h0, k);
                const float hk1 = bcast(h0, k + 1);
                ga  = __builtin_fmaf(whh0_a[k],     hk0, ga);
                gb  = __builtin_fmaf(whh0_b[k],     hk0, gb);
                ga2 = __builtin_fmaf(whh0_a[k + 1], hk1, ga2);
                gb2 = __builtin_fmaf(whh0_b[k + 1], hk1, gb2);
            }
            ga += ga2; gb += gb2;

            float act_a = __builtin_fmaf(mA, fast_rcp(1.0f + __expf(ga * sclA)), cAdd);
            float act_b = sigm(gb);
            float oa = __shfl_xor(act_a, 32);
            float ob = __shfl_xor(act_b, 32);
            {
                const float iv = hi ? oa : act_a;
                const float fv = hi ? ob : act_b;
                const float gv = hi ? act_a : oa;
                const float ov = hi ? act_b : ob;
                c0 = __builtin_fmaf(fv, c0, iv * gv);
                h0 = ov * tanh_fast(c0);
            }

            // ================= layer 1 =================
            float p_a = ba1, p_b = bb1, q_a = 0.0f, q_b = 0.0f;
            #pragma unroll
            for (int k = 0; k < HID; ++k) {
                const float hk0 = bcast(h0, k);
                const float hk1 = bcast(h1, k);
                p_a = __builtin_fmaf(wih1_a[k], hk0, p_a);
                p_b = __builtin_fmaf(wih1_b[k], hk0, p_b);
                q_a = __builtin_fmaf(whh1_a[k], hk1, q_a);
                q_b = __builtin_fmaf(whh1_b[k], hk1, q_b);
            }
            const float ga1 = p_a + q_a;
            const float gb1 = p_b + q_b;

            float act_a1 = __builtin_fmaf(mA, fast_rcp(1.0f + __expf(ga1 * sclA)), cAdd);
            float act_b1 = sigm(gb1);
            float oa1 = __shfl_xor(act_a1, 32);
            float ob1 = __shfl_xor(act_b1, 32);
            {
                const float iv = hi ? oa1 : act_a1;
                const float fv = hi ? ob1 : act_b1;
                const float gv = hi ? act_a1 : oa1;
                const float ov = hi ? act_b1 : ob1;
                c1 = __builtin_fmaf(fv, c1, iv * gv);
                h1 = ov * tanh_fast(c1);
            }

            // ================= linear head =================
            float p = wl * h1;            // wl==0 on half1 -> 64-lane sum == y-b
            #pragma unroll
            for (int m = 32; m >= 1; m >>= 1) p += __shfl_xor(p, m);
            const float y = p + bl;
            ychunk = (lane == tt) ? y : ychunk;
        }

        orow[tc * 64 + lane] = ychunk;   // coalesced store, 64 outputs
    }
}

extern "C" void kernel_launch(void* const* d_in, const int* in_sizes, int n_in,
                              void* d_out, int out_size, void* d_ws, size_t ws_size,
                              hipStream_t stream) {
    const float* x    = (const float*)d_in[0];
    const float* Wih0 = (const float*)d_in[1];
    const float* Whh0 = (const float*)d_in[2];
    const float* bih0 = (const float*)d_in[3];
    const float* bhh0 = (const float*)d_in[4];
    const float* Wih1 = (const float*)d_in[5];
    const float* Whh1 = (const float*)d_in[6];
    const float* bih1 = (const float*)d_in[7];
    const float* bhh1 = (const float*)d_in[8];
    const float* Wlin = (const float*)d_in[9];
    const float* blin = (const float*)d_in[10];
    float* out = (float*)d_out;

    dim3 block(256);
    dim3 grid(BATCH / (256 / 64));   // 4 waves/block, 1 batch element per wave
    hipLaunchKernelGGL(lstm2_kernel, grid, block, 0, stream,
                       x, Wih0, Whh0, bih0, bhh0, Wih1, Whh1, bih1, bhh1,
                       Wlin, blin, out);
}